// Round 8
// baseline (293.965 us; speedup 1.0000x reference)
//
#include <hip/hip_runtime.h>
#include <hip/hip_bf16.h>
#include <cmath>

#define NN 100000
#define NE 1600000
#define NBATCH 64
#define NB 391        // buckets of 256 nodes (dst>>8)
#define NBP 512       // padded bucket count
#define BCAP 6144     // fixed bucket capacity (raw <=5120 + 3*256 align pad + slack)
#define NPAD (NB * BCAP)

typedef __attribute__((ext_vector_type(8))) _Float16 f16x8;
typedef __attribute__((ext_vector_type(4))) float f32x4;
typedef __attribute__((ext_vector_type(2))) float f32x2;
typedef __attribute__((ext_vector_type(4))) unsigned int u32x4;

__device__ __forceinline__ void atomAdd(float* p, float v) {
  unsafeAtomicAdd(p, v);
}

__device__ __forceinline__ unsigned char f2fp8(float f) {
  int pk = __builtin_amdgcn_cvt_pk_fp8_f32(f, f, 0, false);
  return (unsigned char)(pk & 0xff);
}

__device__ __forceinline__ u32x4 ldnt(const u32x4* p) {
  return __builtin_nontemporal_load(p);
}

// accumulate 16 fp8 bytes (one uint4) into 8 f32x2 accumulators
__device__ __forceinline__ void acc16(uint4 v, f32x2* acc) {
  acc[0] += __builtin_amdgcn_cvt_pk_f32_fp8(v.x, false);
  acc[1] += __builtin_amdgcn_cvt_pk_f32_fp8(v.x, true);
  acc[2] += __builtin_amdgcn_cvt_pk_f32_fp8(v.y, false);
  acc[3] += __builtin_amdgcn_cvt_pk_f32_fp8(v.y, true);
  acc[4] += __builtin_amdgcn_cvt_pk_f32_fp8(v.z, false);
  acc[5] += __builtin_amdgcn_cvt_pk_f32_fp8(v.z, true);
  acc[6] += __builtin_amdgcn_cvt_pk_f32_fp8(v.w, false);
  acc[7] += __builtin_amdgcn_cvt_pk_f32_fp8(v.w, true);
}

// ---- bin edges into fixed-capacity bucket regions (LDS counting sort / 4096-chunk) ----
__global__ __launch_bounds__(256) void k_bin(const int* __restrict__ src,
    const int* __restrict__ dst, int* __restrict__ bucketCnt, unsigned* __restrict__ pairs,
    const float* __restrict__ W2, const float* __restrict__ W3, const float* __restrict__ W4,
    _Float16* __restrict__ Wt2, _Float16* __restrict__ Wt3, _Float16* __restrict__ Wt4) {
  __shared__ int hist[NBP];
  __shared__ int scn[NBP];
  __shared__ int ofs[NBP];
  __shared__ int gbase[NBP];
  __shared__ unsigned buf[4096];
  __shared__ unsigned short bufb[4096];
  const int base = blockIdx.x * 4096;
  const int n = (NE - base < 4096) ? NE - base : 4096;
  for (int i = threadIdx.x; i < NBP; i += 256) hist[i] = 0;
  __syncthreads();

  int myS[16], myD[16];
  int nloc = 0;
  for (int i = threadIdx.x, j = 0; i < n; i += 256, ++j) {
    myS[j] = src[base + i];
    myD[j] = dst[base + i];
    atomicAdd(&hist[myD[j] >> 8], 1);
    nloc = j + 1;
  }
  __syncthreads();

  scn[threadIdx.x] = hist[threadIdx.x];
  scn[threadIdx.x + 256] = hist[threadIdx.x + 256];
  __syncthreads();
  for (int off = 1; off < NBP; off <<= 1) {
    const int i0 = threadIdx.x, i1 = threadIdx.x + 256;
    int t0 = (i0 >= off) ? scn[i0 - off] : 0;
    int t1 = (i1 >= off) ? scn[i1 - off] : 0;
    __syncthreads();
    scn[i0] += t0;
    scn[i1] += t1;
    __syncthreads();
  }
  ofs[threadIdx.x] = scn[threadIdx.x] - hist[threadIdx.x];
  ofs[threadIdx.x + 256] = scn[threadIdx.x + 256] - hist[threadIdx.x + 256];
  for (int b = threadIdx.x; b < NB; b += 256) {
    int c = hist[b];
    if (c) gbase[b] = b * BCAP + atomicAdd(&bucketCnt[b], c);
  }
  __syncthreads();

  for (int j = 0; j < nloc; ++j) {
    int b = myD[j] >> 8;
    int slot = atomicAdd(&ofs[b], 1);
    buf[slot] = ((unsigned)myS[j] << 8) | ((unsigned)myD[j] & 255u);
    bufb[slot] = (unsigned short)b;
  }
  __syncthreads();

  for (int i = threadIdx.x; i < n; i += 256) {
    int b = (int)bufb[i];
    int ex = scn[b] - hist[b];
    pairs[gbase[b] + (i - ex)] = buf[i];
  }

  int idx = blockIdx.x * 256 + threadIdx.x;
  if (idx < 2048) {
    int k = idx / 64, m = idx - k * 64;
    Wt2[m * 32 + k] = (_Float16)W2[idx];
  } else if (idx < 10240) {
    int j = idx - 2048;
    int k = j / 128, m = j - k * 128;
    Wt3[m * 64 + k] = (_Float16)W3[j];
  } else if (idx < 43008) {
    int j = idx - 10240;
    int k = j / 256, m = j - k * 256;
    Wt4[m * 128 + k] = (_Float16)W4[j];
  }
}

// ---- per-bucket: count + local scan (16B-aligned row starts) -> rowbeg/rowend/dinv
//      + csrc fill (pads -> sentinel row NN) + batch hist + xs8 pack + zero pad-rows ----
__global__ __launch_bounds__(256) void k_cntfill(const unsigned* __restrict__ pairs,
    const int* __restrict__ bucketCnt, const int* __restrict__ batch,
    const float* __restrict__ x, int* __restrict__ rowbeg, int* __restrict__ rowend,
    float* __restrict__ dinv, int* __restrict__ csrc, float* __restrict__ pcnt,
    _Float16* __restrict__ xs8, unsigned char* __restrict__ F0,
    unsigned char* __restrict__ F1, unsigned char* __restrict__ F2) {
  __shared__ int c[256];
  __shared__ int scn[256];
  __shared__ int rowb[256];
  __shared__ int ofs[256];
  __shared__ int h[64];
  const int tid = threadIdx.x;
  c[tid] = 0; ofs[tid] = 0;
  if (tid < 64) h[tid] = 0;
  __syncthreads();
  const int b = blockIdx.x;
  const int s = b * BCAP;
  const int e = s + bucketCnt[b];
  for (int i = s + tid; i < e; i += 256) atomicAdd(&c[pairs[i] & 255u], 1);
  __syncthreads();
  const int v = c[tid];
  const int pv = (v + 3) & ~3;      // 16B-aligned slot size
  scn[tid] = pv;
  __syncthreads();
  for (int off = 1; off < 256; off <<= 1) {
    int t = (tid >= off) ? scn[tid - off] : 0;
    __syncthreads();
    scn[tid] += t;
    __syncthreads();
  }
  rowb[tid] = s + scn[tid] - pv;
  const int node = b * 256 + tid;
  rowbeg[node] = rowb[tid];
  rowend[node] = rowb[tid] + v;
  // sentinel pad slots -> row NN (zero features)
  for (int p = v; p < pv; ++p) csrc[rowb[tid] + p] = NN;
  if (node < NN) {
    const float di = rsqrtf((float)v + 1.0f);
    dinv[node] = di;
    f16x8 o = {0, 0, 0, 0, 0, 0, 0, 0};
    o[0] = (_Float16)(x[(size_t)node * 5 + 0] * di);
    o[1] = (_Float16)(x[(size_t)node * 5 + 1] * di);
    o[2] = (_Float16)(x[(size_t)node * 5 + 2] * di);
    o[3] = (_Float16)(x[(size_t)node * 5 + 3] * di);
    o[4] = (_Float16)(x[(size_t)node * 5 + 4] * di);
    *(f16x8*)(xs8 + (size_t)node * 8) = o;
    atomicAdd(&h[batch[node]], 1);
  }
  // zero the sentinel feature rows (row NN of each table)
  if (b == 0 && tid < 15) {
    const uint4 z = make_uint4(0u, 0u, 0u, 0u);
    if (tid < 1)      ((uint4*)(xs8 + (size_t)NN * 8))[tid] = z;
    else if (tid < 3) ((uint4*)(F0 + (size_t)NN * 32))[tid - 1] = z;
    else if (tid < 7) ((uint4*)(F1 + (size_t)NN * 64))[tid - 3] = z;
    else              ((uint4*)(F2 + (size_t)NN * 128))[tid - 7] = z;
  }
  __syncthreads();
  for (int i = s + tid; i < e; i += 256) {
    unsigned p = pairs[i];
    int t = (int)(p & 255u);
    int pos = rowb[t] + atomicAdd(&ofs[t], 1);
    csrc[pos] = (int)(p >> 8);
  }
  if (tid < 64 && h[tid]) atomAdd(&pcnt[tid], (float)h[tid]);
}

// ================== phase args ==================
struct MegaArgs {
  const _Float16* xs8;
  const int* rowbeg; const int* rowend; const int* csrc;
  const float* dinv;
  const float* W1; const float* b1;
  unsigned char* F0;
  const _Float16* Wt2; const float* b2;
  unsigned char* F1;
  const _Float16* Wt3; const float* b3;
  unsigned char* F2;
  const _Float16* Wt4; const float* b4;
  const int* batch; float* pooled; const float* pcnt;
  const float* fc1w; const float* fc1b; const float* fc2w; const float* fc2b;
  float* out;
};

// ---- layer1: fp16 xs8 gather (uint4 index stream, 8 loads in flight) + 5->32 GEMM ----
__global__ __launch_bounds__(256) void kw_l1(MegaArgs a) {
  __shared__ float w_s[160];
  __shared__ float b_s[32];
  const int tid = threadIdx.x;
  if (tid < 160) w_s[tid] = a.W1[tid];
  if (tid < 32) b_s[tid] = a.b1[tid];
  __syncthreads();
  const int r = blockIdx.x * 256 + tid;
  if (r >= NN) return;
  const float di = a.dinv[r];
  const _Float16* xs = a.xs8;
  f16x8 av = *(const f16x8*)(xs + (size_t)r * 8);
  f16x8 a0 = {0,0,0,0,0,0,0,0}, a1 = {0,0,0,0,0,0,0,0};
  f16x8 a2 = {0,0,0,0,0,0,0,0}, a3 = {0,0,0,0,0,0,0,0};
  const int eb = a.rowbeg[r];
  const int nIt = (a.rowend[r] - eb + 3) >> 2;
  const u32x4* cp = (const u32x4*)(a.csrc + eb);
  u32x4 i0 = ldnt(cp), i1 = ldnt(cp + 1);
  int it = 0;
  for (; it + 2 <= nIt; it += 2) {
    const f16x8 f0 = *(const f16x8*)(xs + (size_t)i0.x * 8);
    const f16x8 f1 = *(const f16x8*)(xs + (size_t)i0.y * 8);
    const f16x8 f2 = *(const f16x8*)(xs + (size_t)i0.z * 8);
    const f16x8 f3 = *(const f16x8*)(xs + (size_t)i0.w * 8);
    const f16x8 f4 = *(const f16x8*)(xs + (size_t)i1.x * 8);
    const f16x8 f5 = *(const f16x8*)(xs + (size_t)i1.y * 8);
    const f16x8 f6 = *(const f16x8*)(xs + (size_t)i1.z * 8);
    const f16x8 f7 = *(const f16x8*)(xs + (size_t)i1.w * 8);
    const u32x4 n0 = ldnt(cp + it + 2), n1 = ldnt(cp + it + 3);
    a0 += f0; a1 += f1; a2 += f2; a3 += f3;
    a0 += f4; a1 += f5; a2 += f6; a3 += f7;
    i0 = n0; i1 = n1;
  }
  if (it < nIt) {
    const f16x8 f0 = *(const f16x8*)(xs + (size_t)i0.x * 8);
    const f16x8 f1 = *(const f16x8*)(xs + (size_t)i0.y * 8);
    const f16x8 f2 = *(const f16x8*)(xs + (size_t)i0.z * 8);
    const f16x8 f3 = *(const f16x8*)(xs + (size_t)i0.w * 8);
    a0 += f0; a1 += f1; a2 += f2; a3 += f3;
  }
  a0 += a1; a2 += a3; a0 += a2; av += a0;
  const float f0 = (float)av[0] * di, f1 = (float)av[1] * di, f2 = (float)av[2] * di,
              f3 = (float)av[3] * di, f4 = (float)av[4] * di;
  float v[32];
#pragma unroll
  for (int j = 0; j < 32; ++j) {
    float s = b_s[j] + f0 * w_s[j] + f1 * w_s[32 + j] + f2 * w_s[64 + j]
                     + f3 * w_s[96 + j] + f4 * w_s[128 + j];
    v[j] = fmaxf(s, 0.f) * di;
  }
  unsigned u[8];
#pragma unroll
  for (int g2 = 0; g2 < 8; ++g2) {
    int uu = 0;
    uu = __builtin_amdgcn_cvt_pk_fp8_f32(v[4 * g2],     v[4 * g2 + 1], uu, false);
    uu = __builtin_amdgcn_cvt_pk_fp8_f32(v[4 * g2 + 2], v[4 * g2 + 3], uu, true);
    u[g2] = (unsigned)uu;
  }
  uint4* op = (uint4*)(a.F0 + (size_t)r * 32);
  op[0] = make_uint4(u[0], u[1], u[2], u[3]);
  op[1] = make_uint4(u[4], u[5], u[6], u[7]);
}

// ---- fused CSR gather + MFMA GEMM.
//      BROWS rows/tile, THREADS threads: TPR=K/16 lanes/row, uint4 index stream,
//      8 feature + 2 index loads in flight, single gather pass/thread (short chains),
//      small blocks -> fine scheduling granularity + low sync skew.
//      MODE 0: fp8 out (pre-scaled by dinv); MODE 1: fused mean-pool ----
template<int K, int M, int BROWS, int MODE, int THREADS>
__global__ __launch_bounds__(THREADS) void kw_fgemm(MegaArgs a,
    const unsigned char* __restrict__ in,
    const _Float16* __restrict__ Wt, const float* __restrict__ bias,
    unsigned char* __restrict__ outp) {
  constexpr int KC = 32;              // one 16x16x32 MFMA consumes 32 k's per chunk
  constexpr int KP = K + 8;
  constexpr int NW = THREADS / 64;    // waves per block
  constexpr int MW = M / NW;          // output cols per wave
  constexpr int CTW = MW / 16;
  constexpr int RT = BROWS / 16;      // row tiles
  constexpr int TPR = K / 16;         // lanes per row (2/4/8), 16B contiguous each
  constexpr int RPP = THREADS / TPR;  // rows per pass
  constexpr int NPASS = (BROWS + RPP - 1) / RPP;
  __shared__ _Float16 a_s[BROWS * KP];
  const int tid = threadIdx.x;
  const int wave = tid >> 6, lane = tid & 63;
  const int m16 = lane & 15, q = lane >> 4;
  const int r0 = blockIdx.x * BROWS;

  // ---- fused gather ----
  {
    const int rowg = tid / TPR;
    const int c = (tid % TPR) * 16;   // fp8-byte offset within row
    const unsigned char* bp = in + c;
#pragma unroll
    for (int pass = 0; pass < NPASS; ++pass) {
      const int row = pass * RPP + rowg;
      if (NPASS > 1 && row >= BROWS) break;
      const int r = r0 + row;
      f32x2 acc8[8];
#pragma unroll
      for (int i = 0; i < 8; ++i) acc8[i] = (f32x2){0.f, 0.f};
      float di = 0.f;
      if (r < NN) {
        di = a.dinv[r];
        const int eb = a.rowbeg[r];
        const int nIt = (a.rowend[r] - eb + 3) >> 2;
        const u32x4* cp = (const u32x4*)(a.csrc + eb);
        u32x4 i0 = ldnt(cp), i1 = ldnt(cp + 1);
        acc16(*(const uint4*)(bp + (size_t)r * K), acc8);   // self term
        int it = 0;
        for (; it + 2 <= nIt; it += 2) {
          const uint4 f0 = *(const uint4*)(bp + (size_t)i0.x * K);
          const uint4 f1 = *(const uint4*)(bp + (size_t)i0.y * K);
          const uint4 f2 = *(const uint4*)(bp + (size_t)i0.z * K);
          const uint4 f3 = *(const uint4*)(bp + (size_t)i0.w * K);
          const uint4 f4 = *(const uint4*)(bp + (size_t)i1.x * K);
          const uint4 f5 = *(const uint4*)(bp + (size_t)i1.y * K);
          const uint4 f6 = *(const uint4*)(bp + (size_t)i1.z * K);
          const uint4 f7 = *(const uint4*)(bp + (size_t)i1.w * K);
          const u32x4 n0 = ldnt(cp + it + 2), n1 = ldnt(cp + it + 3);
          acc16(f0, acc8); acc16(f1, acc8); acc16(f2, acc8); acc16(f3, acc8);
          acc16(f4, acc8); acc16(f5, acc8); acc16(f6, acc8); acc16(f7, acc8);
          i0 = n0; i1 = n1;
        }
        if (it < nIt) {
          const uint4 f0 = *(const uint4*)(bp + (size_t)i0.x * K);
          const uint4 f1 = *(const uint4*)(bp + (size_t)i0.y * K);
          const uint4 f2 = *(const uint4*)(bp + (size_t)i0.z * K);
          const uint4 f3 = *(const uint4*)(bp + (size_t)i0.w * K);
          acc16(f0, acc8); acc16(f1, acc8); acc16(f2, acc8); acc16(f3, acc8);
        }
      }
      _Float16 h[16];
#pragma unroll
      for (int i = 0; i < 8; ++i) {
        h[2 * i]     = (_Float16)(acc8[i].x * di);
        h[2 * i + 1] = (_Float16)(acc8[i].y * di);
      }
      *(uint4*)&a_s[row * KP + c]     = *(uint4*)&h[0];
      *(uint4*)&a_s[row * KP + c + 8] = *(uint4*)&h[8];
    }
  }
  __syncthreads();

  // ---- GEMM: A from LDS, B direct from global (L2-broadcast), no syncs ----
  f32x4 acc[RT][CTW];
#pragma unroll
  for (int rt = 0; rt < RT; ++rt)
#pragma unroll
    for (int ct = 0; ct < CTW; ++ct) acc[rt][ct] = (f32x4){0.f, 0.f, 0.f, 0.f};

  const _Float16* wp = Wt + (size_t)(wave * MW) * K + q * 8;
#pragma unroll
  for (int kc = 0; kc < K; kc += KC) {
    f16x8 bfr[CTW];
#pragma unroll
    for (int ct = 0; ct < CTW; ++ct)
      bfr[ct] = *(const f16x8*)(wp + (size_t)(ct * 16 + m16) * K + kc);
#pragma unroll
    for (int rt = 0; rt < RT; ++rt) {
      f16x8 afr = *(const f16x8*)&a_s[(rt * 16 + m16) * KP + kc + q * 8];
#pragma unroll
      for (int ct = 0; ct < CTW; ++ct)
        acc[rt][ct] = __builtin_amdgcn_mfma_f32_16x16x32_f16(afr, bfr[ct], acc[rt][ct], 0, 0, 0);
    }
  }

  if constexpr (MODE == 1) {
    const int rlast = (r0 + BROWS - 1 < NN) ? r0 + BROWS - 1 : NN - 1;
    const int bmin = a.batch[r0];
    const int bmax = a.batch[rlast];
    int rowb[RT][4];
#pragma unroll
    for (int rt = 0; rt < RT; ++rt)
#pragma unroll
      for (int reg = 0; reg < 4; ++reg) {
        const int row = r0 + rt * 16 + q * 4 + reg;
        rowb[rt][reg] = (row < NN) ? a.batch[row] : -1;
      }
#pragma unroll
    for (int ct = 0; ct < CTW; ++ct) {
      const int col = wave * MW + ct * 16 + m16;
      const float bv = bias[col];
      for (int b = bmin; b <= bmax; ++b) {
        float s = 0.f;
#pragma unroll
        for (int rt = 0; rt < RT; ++rt)
#pragma unroll
          for (int reg = 0; reg < 4; ++reg)
            if (rowb[rt][reg] == b) s += fmaxf(acc[rt][ct][reg] + bv, 0.f);
        s += __shfl_xor(s, 16);
        s += __shfl_xor(s, 32);
        if (q == 0) atomAdd(&a.pooled[b * M + col], s);
      }
    }
  } else {
#pragma unroll
    for (int rt = 0; rt < RT; ++rt) {
#pragma unroll
      for (int ct = 0; ct < CTW; ++ct) {
        const int col = wave * MW + ct * 16 + m16;
        const float bv = bias[col];
#pragma unroll
        for (int reg = 0; reg < 4; ++reg) {
          const int row = r0 + rt * 16 + q * 4 + reg;
          if (row < NN) {
            float vv = fmaxf(acc[rt][ct][reg] + bv, 0.f) * a.dinv[row];
            outp[(size_t)row * M + col] = f2fp8(vv);
          }
        }
      }
    }
  }
}

// ---- MLP head + log_softmax ----
__global__ __launch_bounds__(256) void kw_mlp(MegaArgs a) {
  __shared__ float p[256];
  __shared__ float h1[100];
  __shared__ float lo[10];
  const int tid = threadIdx.x;
  const int b = blockIdx.x;
  const float inv = 1.0f / fmaxf(a.pcnt[b], 1.0f);
  p[tid] = a.pooled[b * 256 + tid] * inv;
  __syncthreads();
  for (int j = tid; j < 100; j += 256) {
    float s = a.fc1b[j];
    for (int k = 0; k < 256; ++k) s += p[k] * a.fc1w[k * 100 + j];
    h1[j] = fmaxf(s, 0.f);
  }
  __syncthreads();
  if (tid < 10) {
    float s = a.fc2b[tid];
    for (int k = 0; k < 100; ++k) s += h1[k] * a.fc2w[k * 10 + tid];
    lo[tid] = s;
  }
  __syncthreads();
  if (tid == 0) {
    float m = lo[0];
    for (int j = 1; j < 10; ++j) m = fmaxf(m, lo[j]);
    float ssum = 0.f;
    for (int j = 0; j < 10; ++j) ssum += expf(lo[j] - m);
    float lse = m + logf(ssum);
    for (int j = 0; j < 10; ++j) a.out[b * 10 + j] = lo[j] - lse;
  }
}

extern "C" void kernel_launch(void* const* d_in, const int* in_sizes, int n_in,
                              void* d_out, int out_size, void* d_ws, size_t ws_size,
                              hipStream_t stream) {
  const float* x     = (const float*)d_in[0];
  const int*   ei    = (const int*)d_in[1];
  const int*   batch = (const int*)d_in[2];
  const float* W1 = (const float*)d_in[3];  const float* b1 = (const float*)d_in[4];
  const float* W2 = (const float*)d_in[5];  const float* b2 = (const float*)d_in[6];
  const float* W3 = (const float*)d_in[7];  const float* b3 = (const float*)d_in[8];
  const float* W4 = (const float*)d_in[9];  const float* b4 = (const float*)d_in[10];
  const float* fc1w = (const float*)d_in[11]; const float* fc1b = (const float*)d_in[12];
  const float* fc2w = (const float*)d_in[13]; const float* fc2b = (const float*)d_in[14];
  float* out = (float*)d_out;

  const int* src = ei;
  const int* dst = ei + NE;

  // ---- workspace layout (pooled|pcnt|bucketCnt adjacent -> single memset) ----
  float* ws = (float*)d_ws;
  float* pooled = ws;                          // 16384
  float* pcnt   = pooled + 16384;              // 64
  int*   bucketCnt = (int*)(pcnt + 64);        // 512
  float* dinv   = (float*)(bucketCnt + 512);   // 100352
  int*   rowbeg = (int*)(dinv + 100352);       // 100352
  int*   rowend = rowbeg + 100352;             // 100352
  int*   csrc   = rowend + 100352;             // NPAD
  unsigned* pairs = (unsigned*)(csrc + NPAD);  // NPAD (packed u32)
  _Float16* xs8 = (_Float16*)(pairs + NPAD);   // (NN+1)*8 halfs (pad 800768)
  unsigned char* F0 = (unsigned char*)(xs8 + 800768);  // (NN+1)*32 bytes (fp8)
  unsigned char* F1 = F0 + 3200128;                    // (NN+1)*64 bytes (fp8)
  unsigned char* F2 = F1 + 6400128;                    // (NN+1)*128 bytes (fp8)
  _Float16* Wt2 = (_Float16*)(F2 + 12800128);  // 32*64
  _Float16* Wt3 = Wt2 + 32 * 64;               // 64*128
  _Float16* Wt4 = Wt3 + 64 * 128;              // 128*256

  // ---- CSR build (memset + 2 kernels) ----
  (void)hipMemsetAsync(pooled, 0, (16384 + 64 + 512) * sizeof(float), stream);
  k_bin<<<(NE + 4095) / 4096, 256, 0, stream>>>(src, dst, bucketCnt, pairs,
                                                W2, W3, W4, Wt2, Wt3, Wt4);
  k_cntfill<<<NB, 256, 0, stream>>>(pairs, bucketCnt, batch, x,
                                    rowbeg, rowend, dinv, csrc, pcnt, xs8,
                                    F0, F1, F2);

  // ---- compute phases (gather fused into each GEMM; 256-thread 1-pass tiles) ----
  MegaArgs m;
  m.xs8 = xs8; m.rowbeg = rowbeg; m.rowend = rowend; m.csrc = csrc;
  m.dinv = dinv;
  m.W1 = W1; m.b1 = b1; m.F0 = F0;
  m.Wt2 = Wt2; m.b2 = b2; m.F1 = F1;
  m.Wt3 = Wt3; m.b3 = b3; m.F2 = F2;
  m.Wt4 = Wt4; m.b4 = b4;
  m.batch = batch; m.pooled = pooled; m.pcnt = pcnt;
  m.fc1w = fc1w; m.fc1b = fc1b; m.fc2w = fc2w; m.fc2b = fc2b;
  m.out = out;

  kw_l1<<<(NN + 255) / 256, 256, 0, stream>>>(m);
  kw_fgemm<32, 64, 64, 0, 128><<<(NN + 63) / 64, 128, 0, stream>>>(m, F0, Wt2, b2, F1);
  kw_fgemm<64, 128, 64, 0, 256><<<(NN + 63) / 64, 256, 0, stream>>>(m, F1, Wt3, b3, F2);
  kw_fgemm<128, 256, 32, 1, 256><<<(NN + 31) / 32, 256, 0, stream>>>(m, F2, Wt4, b4, nullptr);
  kw_mlp<<<NBATCH, 256, 0, stream>>>(m);
}

// Round 9
// 276.952 us; speedup vs baseline: 1.0614x; 1.0614x over previous
//
#include <hip/hip_runtime.h>
#include <hip/hip_bf16.h>
#include <cmath>

#define NN 100000
#define NE 1600000
#define NBATCH 64
#define NB 391        // buckets of 256 nodes (dst>>8)
#define NBP 512       // padded bucket count
#define BCAP 6144     // fixed bucket capacity (raw <=5120 + 3*256 align pad + slack)
#define NPAD (NB * BCAP)

typedef __attribute__((ext_vector_type(8))) _Float16 f16x8;
typedef __attribute__((ext_vector_type(4))) float f32x4;
typedef __attribute__((ext_vector_type(2))) float f32x2;
typedef __attribute__((ext_vector_type(4))) unsigned int u32x4;

__device__ __forceinline__ void atomAdd(float* p, float v) {
  unsafeAtomicAdd(p, v);
}

__device__ __forceinline__ unsigned char f2fp8(float f) {
  int pk = __builtin_amdgcn_cvt_pk_fp8_f32(f, f, 0, false);
  return (unsigned char)(pk & 0xff);
}

__device__ __forceinline__ u32x4 ldnt(const u32x4* p) {
  return __builtin_nontemporal_load(p);
}

// accumulate 16 fp8 bytes (one uint4) into 8 f32x2 accumulators
__device__ __forceinline__ void acc16(uint4 v, f32x2* acc) {
  acc[0] += __builtin_amdgcn_cvt_pk_f32_fp8(v.x, false);
  acc[1] += __builtin_amdgcn_cvt_pk_f32_fp8(v.x, true);
  acc[2] += __builtin_amdgcn_cvt_pk_f32_fp8(v.y, false);
  acc[3] += __builtin_amdgcn_cvt_pk_f32_fp8(v.y, true);
  acc[4] += __builtin_amdgcn_cvt_pk_f32_fp8(v.z, false);
  acc[5] += __builtin_amdgcn_cvt_pk_f32_fp8(v.z, true);
  acc[6] += __builtin_amdgcn_cvt_pk_f32_fp8(v.w, false);
  acc[7] += __builtin_amdgcn_cvt_pk_f32_fp8(v.w, true);
}

// ---- bin edges into fixed-capacity bucket regions (LDS counting sort / 4096-chunk) ----
__global__ __launch_bounds__(256) void k_bin(const int* __restrict__ src,
    const int* __restrict__ dst, int* __restrict__ bucketCnt, unsigned* __restrict__ pairs,
    const float* __restrict__ W2, const float* __restrict__ W3, const float* __restrict__ W4,
    _Float16* __restrict__ Wt2, _Float16* __restrict__ Wt3, _Float16* __restrict__ Wt4) {
  __shared__ int hist[NBP];
  __shared__ int scn[NBP];
  __shared__ int ofs[NBP];
  __shared__ int gbase[NBP];
  __shared__ unsigned buf[4096];
  __shared__ unsigned short bufb[4096];
  const int base = blockIdx.x * 4096;
  const int n = (NE - base < 4096) ? NE - base : 4096;
  for (int i = threadIdx.x; i < NBP; i += 256) hist[i] = 0;
  __syncthreads();

  int myS[16], myD[16];
  int nloc = 0;
  for (int i = threadIdx.x, j = 0; i < n; i += 256, ++j) {
    myS[j] = src[base + i];
    myD[j] = dst[base + i];
    atomicAdd(&hist[myD[j] >> 8], 1);
    nloc = j + 1;
  }
  __syncthreads();

  scn[threadIdx.x] = hist[threadIdx.x];
  scn[threadIdx.x + 256] = hist[threadIdx.x + 256];
  __syncthreads();
  for (int off = 1; off < NBP; off <<= 1) {
    const int i0 = threadIdx.x, i1 = threadIdx.x + 256;
    int t0 = (i0 >= off) ? scn[i0 - off] : 0;
    int t1 = (i1 >= off) ? scn[i1 - off] : 0;
    __syncthreads();
    scn[i0] += t0;
    scn[i1] += t1;
    __syncthreads();
  }
  ofs[threadIdx.x] = scn[threadIdx.x] - hist[threadIdx.x];
  ofs[threadIdx.x + 256] = scn[threadIdx.x + 256] - hist[threadIdx.x + 256];
  for (int b = threadIdx.x; b < NB; b += 256) {
    int c = hist[b];
    if (c) gbase[b] = b * BCAP + atomicAdd(&bucketCnt[b], c);
  }
  __syncthreads();

  for (int j = 0; j < nloc; ++j) {
    int b = myD[j] >> 8;
    int slot = atomicAdd(&ofs[b], 1);
    buf[slot] = ((unsigned)myS[j] << 8) | ((unsigned)myD[j] & 255u);
    bufb[slot] = (unsigned short)b;
  }
  __syncthreads();

  for (int i = threadIdx.x; i < n; i += 256) {
    int b = (int)bufb[i];
    int ex = scn[b] - hist[b];
    pairs[gbase[b] + (i - ex)] = buf[i];
  }

  int idx = blockIdx.x * 256 + threadIdx.x;
  if (idx < 2048) {
    int k = idx / 64, m = idx - k * 64;
    Wt2[m * 32 + k] = (_Float16)W2[idx];
  } else if (idx < 10240) {
    int j = idx - 2048;
    int k = j / 128, m = j - k * 128;
    Wt3[m * 64 + k] = (_Float16)W3[j];
  } else if (idx < 43008) {
    int j = idx - 10240;
    int k = j / 256, m = j - k * 256;
    Wt4[m * 128 + k] = (_Float16)W4[j];
  }
}

// ---- per-bucket: count + local scan (16B-aligned row starts) -> rowbeg/rowend/dinv
//      + csrc fill (pads -> sentinel row NN) + batch hist + xs8 pack + zero pad-rows ----
__global__ __launch_bounds__(256) void k_cntfill(const unsigned* __restrict__ pairs,
    const int* __restrict__ bucketCnt, const int* __restrict__ batch,
    const float* __restrict__ x, int* __restrict__ rowbeg, int* __restrict__ rowend,
    float* __restrict__ dinv, int* __restrict__ csrc, float* __restrict__ pcnt,
    _Float16* __restrict__ xs8, unsigned char* __restrict__ F0,
    unsigned char* __restrict__ F1, unsigned char* __restrict__ F2) {
  __shared__ int c[256];
  __shared__ int scn[256];
  __shared__ int rowb[256];
  __shared__ int ofs[256];
  __shared__ int h[64];
  const int tid = threadIdx.x;
  c[tid] = 0; ofs[tid] = 0;
  if (tid < 64) h[tid] = 0;
  __syncthreads();
  const int b = blockIdx.x;
  const int s = b * BCAP;
  const int e = s + bucketCnt[b];
  for (int i = s + tid; i < e; i += 256) atomicAdd(&c[pairs[i] & 255u], 1);
  __syncthreads();
  const int v = c[tid];
  const int pv = (v + 3) & ~3;      // 16B-aligned slot size
  scn[tid] = pv;
  __syncthreads();
  for (int off = 1; off < 256; off <<= 1) {
    int t = (tid >= off) ? scn[tid - off] : 0;
    __syncthreads();
    scn[tid] += t;
    __syncthreads();
  }
  rowb[tid] = s + scn[tid] - pv;
  const int node = b * 256 + tid;
  rowbeg[node] = rowb[tid];
  rowend[node] = rowb[tid] + v;
  // sentinel pad slots -> row NN (zero features)
  for (int p = v; p < pv; ++p) csrc[rowb[tid] + p] = NN;
  if (node < NN) {
    const float di = rsqrtf((float)v + 1.0f);
    dinv[node] = di;
    f16x8 o = {0, 0, 0, 0, 0, 0, 0, 0};
    o[0] = (_Float16)(x[(size_t)node * 5 + 0] * di);
    o[1] = (_Float16)(x[(size_t)node * 5 + 1] * di);
    o[2] = (_Float16)(x[(size_t)node * 5 + 2] * di);
    o[3] = (_Float16)(x[(size_t)node * 5 + 3] * di);
    o[4] = (_Float16)(x[(size_t)node * 5 + 4] * di);
    *(f16x8*)(xs8 + (size_t)node * 8) = o;
    atomicAdd(&h[batch[node]], 1);
  }
  // zero the sentinel feature rows (row NN of each table)
  if (b == 0 && tid < 15) {
    const uint4 z = make_uint4(0u, 0u, 0u, 0u);
    if (tid < 1)      ((uint4*)(xs8 + (size_t)NN * 8))[tid] = z;
    else if (tid < 3) ((uint4*)(F0 + (size_t)NN * 32))[tid - 1] = z;
    else if (tid < 7) ((uint4*)(F1 + (size_t)NN * 64))[tid - 3] = z;
    else              ((uint4*)(F2 + (size_t)NN * 128))[tid - 7] = z;
  }
  __syncthreads();
  for (int i = s + tid; i < e; i += 256) {
    unsigned p = pairs[i];
    int t = (int)(p & 255u);
    int pos = rowb[t] + atomicAdd(&ofs[t], 1);
    csrc[pos] = (int)(p >> 8);
  }
  if (tid < 64 && h[tid]) atomAdd(&pcnt[tid], (float)h[tid]);
}

// ================== phase args ==================
struct MegaArgs {
  const _Float16* xs8;
  const int* rowbeg; const int* rowend; const int* csrc;
  const float* dinv;
  const float* W1; const float* b1;
  unsigned char* F0;
  const _Float16* Wt2; const float* b2;
  unsigned char* F1;
  const _Float16* Wt3; const float* b3;
  unsigned char* F2;
  const _Float16* Wt4; const float* b4;
  const int* batch; float* pooled; const float* pcnt;
  const float* fc1w; const float* fc1b; const float* fc2w; const float* fc2b;
  float* out;
};

// ---- layer1: fp16 xs8 gather (uint4 index stream, 8 loads in flight) + 5->32 GEMM ----
__global__ __launch_bounds__(256) void kw_l1(MegaArgs a) {
  __shared__ float w_s[160];
  __shared__ float b_s[32];
  const int tid = threadIdx.x;
  if (tid < 160) w_s[tid] = a.W1[tid];
  if (tid < 32) b_s[tid] = a.b1[tid];
  __syncthreads();
  const int r = blockIdx.x * 256 + tid;
  if (r >= NN) return;
  const float di = a.dinv[r];
  const _Float16* xs = a.xs8;
  f16x8 av = *(const f16x8*)(xs + (size_t)r * 8);
  f16x8 a0 = {0,0,0,0,0,0,0,0}, a1 = {0,0,0,0,0,0,0,0};
  f16x8 a2 = {0,0,0,0,0,0,0,0}, a3 = {0,0,0,0,0,0,0,0};
  const int eb = a.rowbeg[r];
  const int nIt = (a.rowend[r] - eb + 3) >> 2;
  const u32x4* cp = (const u32x4*)(a.csrc + eb);
  u32x4 i0 = ldnt(cp), i1 = ldnt(cp + 1);
  int it = 0;
  for (; it + 2 <= nIt; it += 2) {
    const f16x8 f0 = *(const f16x8*)(xs + (size_t)i0.x * 8);
    const f16x8 f1 = *(const f16x8*)(xs + (size_t)i0.y * 8);
    const f16x8 f2 = *(const f16x8*)(xs + (size_t)i0.z * 8);
    const f16x8 f3 = *(const f16x8*)(xs + (size_t)i0.w * 8);
    const f16x8 f4 = *(const f16x8*)(xs + (size_t)i1.x * 8);
    const f16x8 f5 = *(const f16x8*)(xs + (size_t)i1.y * 8);
    const f16x8 f6 = *(const f16x8*)(xs + (size_t)i1.z * 8);
    const f16x8 f7 = *(const f16x8*)(xs + (size_t)i1.w * 8);
    const u32x4 n0 = ldnt(cp + it + 2), n1 = ldnt(cp + it + 3);
    a0 += f0; a1 += f1; a2 += f2; a3 += f3;
    a0 += f4; a1 += f5; a2 += f6; a3 += f7;
    i0 = n0; i1 = n1;
  }
  if (it < nIt) {
    const f16x8 f0 = *(const f16x8*)(xs + (size_t)i0.x * 8);
    const f16x8 f1 = *(const f16x8*)(xs + (size_t)i0.y * 8);
    const f16x8 f2 = *(const f16x8*)(xs + (size_t)i0.z * 8);
    const f16x8 f3 = *(const f16x8*)(xs + (size_t)i0.w * 8);
    a0 += f0; a1 += f1; a2 += f2; a3 += f3;
  }
  a0 += a1; a2 += a3; a0 += a2; av += a0;
  const float f0 = (float)av[0] * di, f1 = (float)av[1] * di, f2 = (float)av[2] * di,
              f3 = (float)av[3] * di, f4 = (float)av[4] * di;
  float v[32];
#pragma unroll
  for (int j = 0; j < 32; ++j) {
    float s = b_s[j] + f0 * w_s[j] + f1 * w_s[32 + j] + f2 * w_s[64 + j]
                     + f3 * w_s[96 + j] + f4 * w_s[128 + j];
    v[j] = fmaxf(s, 0.f) * di;
  }
  unsigned u[8];
#pragma unroll
  for (int g2 = 0; g2 < 8; ++g2) {
    int uu = 0;
    uu = __builtin_amdgcn_cvt_pk_fp8_f32(v[4 * g2],     v[4 * g2 + 1], uu, false);
    uu = __builtin_amdgcn_cvt_pk_fp8_f32(v[4 * g2 + 2], v[4 * g2 + 3], uu, true);
    u[g2] = (unsigned)uu;
  }
  uint4* op = (uint4*)(a.F0 + (size_t)r * 32);
  op[0] = make_uint4(u[0], u[1], u[2], u[3]);
  op[1] = make_uint4(u[4], u[5], u[6], u[7]);
}

// ---- fused CSR gather + MFMA GEMM.
//      BROWS rows/tile, THREADS threads: TPR=K/16 lanes/row, uint4 index stream,
//      8 feature + 2 index loads in flight, single gather pass/thread (short chains),
//      CTW kept at 2 -> VGPR<=64 -> 8 waves/SIMD residency (proven r7 lever).
//      MODE 0: fp8 out (pre-scaled by dinv); MODE 1: fused mean-pool ----
template<int K, int M, int BROWS, int MODE, int THREADS>
__global__ __launch_bounds__(THREADS) void kw_fgemm(MegaArgs a,
    const unsigned char* __restrict__ in,
    const _Float16* __restrict__ Wt, const float* __restrict__ bias,
    unsigned char* __restrict__ outp) {
  constexpr int KC = 32;              // one 16x16x32 MFMA consumes 32 k's per chunk
  constexpr int KP = K + 8;
  constexpr int NW = THREADS / 64;    // waves per block
  constexpr int MW = M / NW;          // output cols per wave
  constexpr int CTW = MW / 16;
  constexpr int RT = BROWS / 16;      // row tiles
  constexpr int TPR = K / 16;         // lanes per row (2/4/8), 16B contiguous each
  constexpr int RPP = THREADS / TPR;  // rows per pass
  constexpr int NPASS = (BROWS + RPP - 1) / RPP;
  __shared__ _Float16 a_s[BROWS * KP];
  const int tid = threadIdx.x;
  const int wave = tid >> 6, lane = tid & 63;
  const int m16 = lane & 15, q = lane >> 4;
  const int r0 = blockIdx.x * BROWS;

  // ---- fused gather ----
  {
    const int rowg = tid / TPR;
    const int c = (tid % TPR) * 16;   // fp8-byte offset within row
    const unsigned char* bp = in + c;
#pragma unroll
    for (int pass = 0; pass < NPASS; ++pass) {
      const int row = pass * RPP + rowg;
      if (NPASS > 1 && row >= BROWS) break;
      const int r = r0 + row;
      f32x2 acc8[8];
#pragma unroll
      for (int i = 0; i < 8; ++i) acc8[i] = (f32x2){0.f, 0.f};
      float di = 0.f;
      if (r < NN) {
        di = a.dinv[r];
        const int eb = a.rowbeg[r];
        const int nIt = (a.rowend[r] - eb + 3) >> 2;
        const u32x4* cp = (const u32x4*)(a.csrc + eb);
        u32x4 i0 = ldnt(cp), i1 = ldnt(cp + 1);
        acc16(*(const uint4*)(bp + (size_t)r * K), acc8);   // self term
        int it = 0;
        for (; it + 2 <= nIt; it += 2) {
          const uint4 f0 = *(const uint4*)(bp + (size_t)i0.x * K);
          const uint4 f1 = *(const uint4*)(bp + (size_t)i0.y * K);
          const uint4 f2 = *(const uint4*)(bp + (size_t)i0.z * K);
          const uint4 f3 = *(const uint4*)(bp + (size_t)i0.w * K);
          const uint4 f4 = *(const uint4*)(bp + (size_t)i1.x * K);
          const uint4 f5 = *(const uint4*)(bp + (size_t)i1.y * K);
          const uint4 f6 = *(const uint4*)(bp + (size_t)i1.z * K);
          const uint4 f7 = *(const uint4*)(bp + (size_t)i1.w * K);
          const u32x4 n0 = ldnt(cp + it + 2), n1 = ldnt(cp + it + 3);
          acc16(f0, acc8); acc16(f1, acc8); acc16(f2, acc8); acc16(f3, acc8);
          acc16(f4, acc8); acc16(f5, acc8); acc16(f6, acc8); acc16(f7, acc8);
          i0 = n0; i1 = n1;
        }
        if (it < nIt) {
          const uint4 f0 = *(const uint4*)(bp + (size_t)i0.x * K);
          const uint4 f1 = *(const uint4*)(bp + (size_t)i0.y * K);
          const uint4 f2 = *(const uint4*)(bp + (size_t)i0.z * K);
          const uint4 f3 = *(const uint4*)(bp + (size_t)i0.w * K);
          acc16(f0, acc8); acc16(f1, acc8); acc16(f2, acc8); acc16(f3, acc8);
        }
      }
      _Float16 h[16];
#pragma unroll
      for (int i = 0; i < 8; ++i) {
        h[2 * i]     = (_Float16)(acc8[i].x * di);
        h[2 * i + 1] = (_Float16)(acc8[i].y * di);
      }
      *(uint4*)&a_s[row * KP + c]     = *(uint4*)&h[0];
      *(uint4*)&a_s[row * KP + c + 8] = *(uint4*)&h[8];
    }
  }
  __syncthreads();

  // ---- GEMM: A from LDS, B direct from global (L2-broadcast), no syncs ----
  f32x4 acc[RT][CTW];
#pragma unroll
  for (int rt = 0; rt < RT; ++rt)
#pragma unroll
    for (int ct = 0; ct < CTW; ++ct) acc[rt][ct] = (f32x4){0.f, 0.f, 0.f, 0.f};

  const _Float16* wp = Wt + (size_t)(wave * MW) * K + q * 8;
#pragma unroll
  for (int kc = 0; kc < K; kc += KC) {
    f16x8 bfr[CTW];
#pragma unroll
    for (int ct = 0; ct < CTW; ++ct)
      bfr[ct] = *(const f16x8*)(wp + (size_t)(ct * 16 + m16) * K + kc);
#pragma unroll
    for (int rt = 0; rt < RT; ++rt) {
      f16x8 afr = *(const f16x8*)&a_s[(rt * 16 + m16) * KP + kc + q * 8];
#pragma unroll
      for (int ct = 0; ct < CTW; ++ct)
        acc[rt][ct] = __builtin_amdgcn_mfma_f32_16x16x32_f16(afr, bfr[ct], acc[rt][ct], 0, 0, 0);
    }
  }

  if constexpr (MODE == 1) {
    const int rlast = (r0 + BROWS - 1 < NN) ? r0 + BROWS - 1 : NN - 1;
    const int bmin = a.batch[r0];
    const int bmax = a.batch[rlast];
    int rowb[RT][4];
#pragma unroll
    for (int rt = 0; rt < RT; ++rt)
#pragma unroll
      for (int reg = 0; reg < 4; ++reg) {
        const int row = r0 + rt * 16 + q * 4 + reg;
        rowb[rt][reg] = (row < NN) ? a.batch[row] : -1;
      }
#pragma unroll
    for (int ct = 0; ct < CTW; ++ct) {
      const int col = wave * MW + ct * 16 + m16;
      const float bv = bias[col];
      for (int b = bmin; b <= bmax; ++b) {
        float s = 0.f;
#pragma unroll
        for (int rt = 0; rt < RT; ++rt)
#pragma unroll
          for (int reg = 0; reg < 4; ++reg)
            if (rowb[rt][reg] == b) s += fmaxf(acc[rt][ct][reg] + bv, 0.f);
        s += __shfl_xor(s, 16);
        s += __shfl_xor(s, 32);
        if (q == 0) atomAdd(&a.pooled[b * M + col], s);
      }
    }
  } else {
#pragma unroll
    for (int rt = 0; rt < RT; ++rt) {
#pragma unroll
      for (int ct = 0; ct < CTW; ++ct) {
        const int col = wave * MW + ct * 16 + m16;
        const float bv = bias[col];
#pragma unroll
        for (int reg = 0; reg < 4; ++reg) {
          const int row = r0 + rt * 16 + q * 4 + reg;
          if (row < NN) {
            float vv = fmaxf(acc[rt][ct][reg] + bv, 0.f) * a.dinv[row];
            outp[(size_t)row * M + col] = f2fp8(vv);
          }
        }
      }
    }
  }
}

// ---- MLP head + log_softmax ----
__global__ __launch_bounds__(256) void kw_mlp(MegaArgs a) {
  __shared__ float p[256];
  __shared__ float h1[100];
  __shared__ float lo[10];
  const int tid = threadIdx.x;
  const int b = blockIdx.x;
  const float inv = 1.0f / fmaxf(a.pcnt[b], 1.0f);
  p[tid] = a.pooled[b * 256 + tid] * inv;
  __syncthreads();
  for (int j = tid; j < 100; j += 256) {
    float s = a.fc1b[j];
    for (int k = 0; k < 256; ++k) s += p[k] * a.fc1w[k * 100 + j];
    h1[j] = fmaxf(s, 0.f);
  }
  __syncthreads();
  if (tid < 10) {
    float s = a.fc2b[tid];
    for (int k = 0; k < 100; ++k) s += h1[k] * a.fc2w[k * 10 + tid];
    lo[tid] = s;
  }
  __syncthreads();
  if (tid == 0) {
    float m = lo[0];
    for (int j = 1; j < 10; ++j) m = fmaxf(m, lo[j]);
    float ssum = 0.f;
    for (int j = 0; j < 10; ++j) ssum += expf(lo[j] - m);
    float lse = m + logf(ssum);
    for (int j = 0; j < 10; ++j) a.out[b * 10 + j] = lo[j] - lse;
  }
}

extern "C" void kernel_launch(void* const* d_in, const int* in_sizes, int n_in,
                              void* d_out, int out_size, void* d_ws, size_t ws_size,
                              hipStream_t stream) {
  const float* x     = (const float*)d_in[0];
  const int*   ei    = (const int*)d_in[1];
  const int*   batch = (const int*)d_in[2];
  const float* W1 = (const float*)d_in[3];  const float* b1 = (const float*)d_in[4];
  const float* W2 = (const float*)d_in[5];  const float* b2 = (const float*)d_in[6];
  const float* W3 = (const float*)d_in[7];  const float* b3 = (const float*)d_in[8];
  const float* W4 = (const float*)d_in[9];  const float* b4 = (const float*)d_in[10];
  const float* fc1w = (const float*)d_in[11]; const float* fc1b = (const float*)d_in[12];
  const float* fc2w = (const float*)d_in[13]; const float* fc2b = (const float*)d_in[14];
  float* out = (float*)d_out;

  const int* src = ei;
  const int* dst = ei + NE;

  // ---- workspace layout (pooled|pcnt|bucketCnt adjacent -> single memset) ----
  float* ws = (float*)d_ws;
  float* pooled = ws;                          // 16384
  float* pcnt   = pooled + 16384;              // 64
  int*   bucketCnt = (int*)(pcnt + 64);        // 512
  float* dinv   = (float*)(bucketCnt + 512);   // 100352
  int*   rowbeg = (int*)(dinv + 100352);       // 100352
  int*   rowend = rowbeg + 100352;             // 100352
  int*   csrc   = rowend + 100352;             // NPAD
  unsigned* pairs = (unsigned*)(csrc + NPAD);  // NPAD (packed u32)
  _Float16* xs8 = (_Float16*)(pairs + NPAD);   // (NN+1)*8 halfs (pad 800768)
  unsigned char* F0 = (unsigned char*)(xs8 + 800768);  // (NN+1)*32 bytes (fp8)
  unsigned char* F1 = F0 + 3200128;                    // (NN+1)*64 bytes (fp8)
  unsigned char* F2 = F1 + 6400128;                    // (NN+1)*128 bytes (fp8)
  _Float16* Wt2 = (_Float16*)(F2 + 12800128);  // 32*64
  _Float16* Wt3 = Wt2 + 32 * 64;               // 64*128
  _Float16* Wt4 = Wt3 + 64 * 128;              // 128*256

  // ---- CSR build (memset + 2 kernels) ----
  (void)hipMemsetAsync(pooled, 0, (16384 + 64 + 512) * sizeof(float), stream);
  k_bin<<<(NE + 4095) / 4096, 256, 0, stream>>>(src, dst, bucketCnt, pairs,
                                                W2, W3, W4, Wt2, Wt3, Wt4);
  k_cntfill<<<NB, 256, 0, stream>>>(pairs, bucketCnt, batch, x,
                                    rowbeg, rowend, dinv, csrc, pcnt, xs8,
                                    F0, F1, F2);

  // ---- compute phases: best measured per-layer configs ----
  //  K=32 : 128 thr, BROWS=64 (unchanged all rounds)
  //  K=64 : 256 thr, BROWS=64, 1-pass (fully-resident grid 1563 @ 8 blk/CU)
  //  K=128: 512 thr, BROWS=64, 1-pass, CTW=2 -> 60 VGPR (r7's 50.5us config)
  MegaArgs m;
  m.xs8 = xs8; m.rowbeg = rowbeg; m.rowend = rowend; m.csrc = csrc;
  m.dinv = dinv;
  m.W1 = W1; m.b1 = b1; m.F0 = F0;
  m.Wt2 = Wt2; m.b2 = b2; m.F1 = F1;
  m.Wt3 = Wt3; m.b3 = b3; m.F2 = F2;
  m.Wt4 = Wt4; m.b4 = b4;
  m.batch = batch; m.pooled = pooled; m.pcnt = pcnt;
  m.fc1w = fc1w; m.fc1b = fc1b; m.fc2w = fc2w; m.fc2b = fc2b;
  m.out = out;

  kw_l1<<<(NN + 255) / 256, 256, 0, stream>>>(m);
  kw_fgemm<32, 64, 64, 0, 128><<<(NN + 63) / 64, 128, 0, stream>>>(m, F0, Wt2, b2, F1);
  kw_fgemm<64, 128, 64, 0, 256><<<(NN + 63) / 64, 256, 0, stream>>>(m, F1, Wt3, b3, F2);
  kw_fgemm<128, 256, 64, 1, 512><<<(NN + 63) / 64, 512, 0, stream>>>(m, F2, Wt4, b4, nullptr);
  kw_mlp<<<NBATCH, 256, 0, stream>>>(m);
}

// Round 10
// 266.143 us; speedup vs baseline: 1.1045x; 1.0406x over previous
//
#include <hip/hip_runtime.h>
#include <hip/hip_bf16.h>
#include <cmath>

#define NN 100000
#define NE 1600000
#define NBATCH 64
#define NB 391        // buckets of 256 nodes (dst>>8)
#define NBP 512       // padded bucket count
#define BCAP 6144     // fixed bucket capacity (raw <=5120 + 3*256 align pad + slack)
#define NPAD (NB * BCAP)

typedef __attribute__((ext_vector_type(8))) _Float16 f16x8;
typedef __attribute__((ext_vector_type(4))) float f32x4;
typedef __attribute__((ext_vector_type(2))) float f32x2;
typedef __attribute__((ext_vector_type(4))) unsigned int u32x4;

__device__ __forceinline__ void atomAdd(float* p, float v) {
  unsafeAtomicAdd(p, v);
}

__device__ __forceinline__ unsigned char f2fp8(float f) {
  int pk = __builtin_amdgcn_cvt_pk_fp8_f32(f, f, 0, false);
  return (unsigned char)(pk & 0xff);
}

__device__ __forceinline__ u32x4 ldnt(const u32x4* p) {
  return __builtin_nontemporal_load(p);
}

// accumulate 16 fp8 bytes (one uint4) into 8 f32x2 accumulators
__device__ __forceinline__ void acc16(uint4 v, f32x2* acc) {
  acc[0] += __builtin_amdgcn_cvt_pk_f32_fp8(v.x, false);
  acc[1] += __builtin_amdgcn_cvt_pk_f32_fp8(v.x, true);
  acc[2] += __builtin_amdgcn_cvt_pk_f32_fp8(v.y, false);
  acc[3] += __builtin_amdgcn_cvt_pk_f32_fp8(v.y, true);
  acc[4] += __builtin_amdgcn_cvt_pk_f32_fp8(v.z, false);
  acc[5] += __builtin_amdgcn_cvt_pk_f32_fp8(v.z, true);
  acc[6] += __builtin_amdgcn_cvt_pk_f32_fp8(v.w, false);
  acc[7] += __builtin_amdgcn_cvt_pk_f32_fp8(v.w, true);
}

// ---- bin edges into fixed-capacity bucket regions (LDS counting sort / 4096-chunk) ----
__global__ __launch_bounds__(256) void k_bin(const int* __restrict__ src,
    const int* __restrict__ dst, int* __restrict__ bucketCnt, unsigned* __restrict__ pairs,
    const float* __restrict__ W2, const float* __restrict__ W3, const float* __restrict__ W4,
    _Float16* __restrict__ Wt2, _Float16* __restrict__ Wt3, _Float16* __restrict__ Wt4) {
  __shared__ int hist[NBP];
  __shared__ int scn[NBP];
  __shared__ int ofs[NBP];
  __shared__ int gbase[NBP];
  __shared__ unsigned buf[4096];
  __shared__ unsigned short bufb[4096];
  const int base = blockIdx.x * 4096;
  const int n = (NE - base < 4096) ? NE - base : 4096;
  for (int i = threadIdx.x; i < NBP; i += 256) hist[i] = 0;
  __syncthreads();

  int myS[16], myD[16];
  int nloc = 0;
  for (int i = threadIdx.x, j = 0; i < n; i += 256, ++j) {
    myS[j] = src[base + i];
    myD[j] = dst[base + i];
    atomicAdd(&hist[myD[j] >> 8], 1);
    nloc = j + 1;
  }
  __syncthreads();

  scn[threadIdx.x] = hist[threadIdx.x];
  scn[threadIdx.x + 256] = hist[threadIdx.x + 256];
  __syncthreads();
  for (int off = 1; off < NBP; off <<= 1) {
    const int i0 = threadIdx.x, i1 = threadIdx.x + 256;
    int t0 = (i0 >= off) ? scn[i0 - off] : 0;
    int t1 = (i1 >= off) ? scn[i1 - off] : 0;
    __syncthreads();
    scn[i0] += t0;
    scn[i1] += t1;
    __syncthreads();
  }
  ofs[threadIdx.x] = scn[threadIdx.x] - hist[threadIdx.x];
  ofs[threadIdx.x + 256] = scn[threadIdx.x + 256] - hist[threadIdx.x + 256];
  for (int b = threadIdx.x; b < NB; b += 256) {
    int c = hist[b];
    if (c) gbase[b] = b * BCAP + atomicAdd(&bucketCnt[b], c);
  }
  __syncthreads();

  for (int j = 0; j < nloc; ++j) {
    int b = myD[j] >> 8;
    int slot = atomicAdd(&ofs[b], 1);
    buf[slot] = ((unsigned)myS[j] << 8) | ((unsigned)myD[j] & 255u);
    bufb[slot] = (unsigned short)b;
  }
  __syncthreads();

  for (int i = threadIdx.x; i < n; i += 256) {
    int b = (int)bufb[i];
    int ex = scn[b] - hist[b];
    pairs[gbase[b] + (i - ex)] = buf[i];
  }

  int idx = blockIdx.x * 256 + threadIdx.x;
  if (idx < 2048) {
    int k = idx / 64, m = idx - k * 64;
    Wt2[m * 32 + k] = (_Float16)W2[idx];
  } else if (idx < 10240) {
    int j = idx - 2048;
    int k = j / 128, m = j - k * 128;
    Wt3[m * 64 + k] = (_Float16)W3[j];
  } else if (idx < 43008) {
    int j = idx - 10240;
    int k = j / 256, m = j - k * 256;
    Wt4[m * 128 + k] = (_Float16)W4[j];
  }
}

// ---- per-bucket: count + local scan (16B-aligned row starts) -> rowbeg/rowend/dinv
//      + csrc fill (pads -> sentinel row NN) + batch hist + xs8 pack + zero pad-rows ----
__global__ __launch_bounds__(256) void k_cntfill(const unsigned* __restrict__ pairs,
    const int* __restrict__ bucketCnt, const int* __restrict__ batch,
    const float* __restrict__ x, int* __restrict__ rowbeg, int* __restrict__ rowend,
    float* __restrict__ dinv, int* __restrict__ csrc, float* __restrict__ pcnt,
    _Float16* __restrict__ xs8, unsigned char* __restrict__ F0,
    unsigned char* __restrict__ F1, unsigned char* __restrict__ F2) {
  __shared__ int c[256];
  __shared__ int scn[256];
  __shared__ int rowb[256];
  __shared__ int ofs[256];
  __shared__ int h[64];
  const int tid = threadIdx.x;
  c[tid] = 0; ofs[tid] = 0;
  if (tid < 64) h[tid] = 0;
  __syncthreads();
  const int b = blockIdx.x;
  const int s = b * BCAP;
  const int e = s + bucketCnt[b];
  for (int i = s + tid; i < e; i += 256) atomicAdd(&c[pairs[i] & 255u], 1);
  __syncthreads();
  const int v = c[tid];
  const int pv = (v + 3) & ~3;      // 16B-aligned slot size
  scn[tid] = pv;
  __syncthreads();
  for (int off = 1; off < 256; off <<= 1) {
    int t = (tid >= off) ? scn[tid - off] : 0;
    __syncthreads();
    scn[tid] += t;
    __syncthreads();
  }
  rowb[tid] = s + scn[tid] - pv;
  const int node = b * 256 + tid;
  rowbeg[node] = rowb[tid];
  rowend[node] = rowb[tid] + v;
  // sentinel pad slots -> row NN (zero features)
  for (int p = v; p < pv; ++p) csrc[rowb[tid] + p] = NN;
  if (node < NN) {
    const float di = rsqrtf((float)v + 1.0f);
    dinv[node] = di;
    f16x8 o = {0, 0, 0, 0, 0, 0, 0, 0};
    o[0] = (_Float16)(x[(size_t)node * 5 + 0] * di);
    o[1] = (_Float16)(x[(size_t)node * 5 + 1] * di);
    o[2] = (_Float16)(x[(size_t)node * 5 + 2] * di);
    o[3] = (_Float16)(x[(size_t)node * 5 + 3] * di);
    o[4] = (_Float16)(x[(size_t)node * 5 + 4] * di);
    *(f16x8*)(xs8 + (size_t)node * 8) = o;
    atomicAdd(&h[batch[node]], 1);
  }
  // zero the sentinel feature rows (row NN of each table)
  if (b == 0 && tid < 15) {
    const uint4 z = make_uint4(0u, 0u, 0u, 0u);
    if (tid < 1)      ((uint4*)(xs8 + (size_t)NN * 8))[tid] = z;
    else if (tid < 3) ((uint4*)(F0 + (size_t)NN * 32))[tid - 1] = z;
    else if (tid < 7) ((uint4*)(F1 + (size_t)NN * 64))[tid - 3] = z;
    else              ((uint4*)(F2 + (size_t)NN * 128))[tid - 7] = z;
  }
  __syncthreads();
  for (int i = s + tid; i < e; i += 256) {
    unsigned p = pairs[i];
    int t = (int)(p & 255u);
    int pos = rowb[t] + atomicAdd(&ofs[t], 1);
    csrc[pos] = (int)(p >> 8);
  }
  if (tid < 64 && h[tid]) atomAdd(&pcnt[tid], (float)h[tid]);
}

// ================== phase args ==================
struct MegaArgs {
  const _Float16* xs8;
  const int* rowbeg; const int* rowend; const int* csrc;
  const float* dinv;
  const float* W1; const float* b1;
  unsigned char* F0;
  const _Float16* Wt2; const float* b2;
  unsigned char* F1;
  const _Float16* Wt3; const float* b3;
  unsigned char* F2;
  const _Float16* Wt4; const float* b4;
  const int* batch; float* pooled; const float* pcnt;
  const float* fc1w; const float* fc1b; const float* fc2w; const float* fc2b;
  float* out;
};

// ---- layer1: 4 lanes/row edge-split gather (uint4 index stream) + shfl reduce +
//      column-split 5->32 GEMM (8 cols/lane), fp8 out. 400k threads fill the machine. ----
__global__ __launch_bounds__(256) void kw_l1(MegaArgs a) {
  __shared__ float w_s[160];
  __shared__ float b_s[32];
  const int tid = threadIdx.x;
  if (tid < 160) w_s[tid] = a.W1[tid];
  if (tid < 32) b_s[tid] = a.b1[tid];
  __syncthreads();
  const int gid = blockIdx.x * 256 + tid;
  const int r = gid >> 2;
  const int eg = gid & 3;
  if (r >= NN) return;
  const float di = a.dinv[r];
  const _Float16* xs = a.xs8;
  f16x8 av = {0,0,0,0,0,0,0,0};
  if (eg == 0) av = *(const f16x8*)(xs + (size_t)r * 8);
  f16x8 a0 = {0,0,0,0,0,0,0,0}, a1 = {0,0,0,0,0,0,0,0};
  f16x8 a2 = {0,0,0,0,0,0,0,0}, a3 = {0,0,0,0,0,0,0,0};
  const int eb = a.rowbeg[r];
  const int nIt = (a.rowend[r] - eb + 3) >> 2;
  const int nL = (nIt - eg + 3) >> 2;
  if (nL > 0) {
    const u32x4* cp = (const u32x4*)(a.csrc + eb) + eg;
    u32x4 i0 = ldnt(cp), i1 = ldnt(cp + 4);
    int k = 0;
    for (; k + 2 <= nL; k += 2) {
      const f16x8 f0 = *(const f16x8*)(xs + (size_t)i0.x * 8);
      const f16x8 f1 = *(const f16x8*)(xs + (size_t)i0.y * 8);
      const f16x8 f2 = *(const f16x8*)(xs + (size_t)i0.z * 8);
      const f16x8 f3 = *(const f16x8*)(xs + (size_t)i0.w * 8);
      const f16x8 f4 = *(const f16x8*)(xs + (size_t)i1.x * 8);
      const f16x8 f5 = *(const f16x8*)(xs + (size_t)i1.y * 8);
      const f16x8 f6 = *(const f16x8*)(xs + (size_t)i1.z * 8);
      const f16x8 f7 = *(const f16x8*)(xs + (size_t)i1.w * 8);
      const u32x4 n0 = ldnt(cp + (k + 2) * 4), n1 = ldnt(cp + (k + 3) * 4);
      a0 += f0; a1 += f1; a2 += f2; a3 += f3;
      a0 += f4; a1 += f5; a2 += f6; a3 += f7;
      i0 = n0; i1 = n1;
    }
    if (k < nL) {
      const f16x8 f0 = *(const f16x8*)(xs + (size_t)i0.x * 8);
      const f16x8 f1 = *(const f16x8*)(xs + (size_t)i0.y * 8);
      const f16x8 f2 = *(const f16x8*)(xs + (size_t)i0.z * 8);
      const f16x8 f3 = *(const f16x8*)(xs + (size_t)i0.w * 8);
      a0 += f0; a1 += f1; a2 += f2; a3 += f3;
    }
  }
  a0 += a1; a2 += a3; a0 += a2; av += a0;
  float f0 = (float)av[0], f1 = (float)av[1], f2 = (float)av[2],
        f3 = (float)av[3], f4 = (float)av[4];
  // reduce partial sums across the 4 edge-group lanes of this row
  f0 += __shfl_xor(f0, 1); f0 += __shfl_xor(f0, 2);
  f1 += __shfl_xor(f1, 1); f1 += __shfl_xor(f1, 2);
  f2 += __shfl_xor(f2, 1); f2 += __shfl_xor(f2, 2);
  f3 += __shfl_xor(f3, 1); f3 += __shfl_xor(f3, 2);
  f4 += __shfl_xor(f4, 1); f4 += __shfl_xor(f4, 2);
  f0 *= di; f1 *= di; f2 *= di; f3 *= di; f4 *= di;
  // 8 output cols per lane
  float v[8];
  const int j0 = eg * 8;
#pragma unroll
  for (int jj = 0; jj < 8; ++jj) {
    const int j = j0 + jj;
    float s = b_s[j] + f0 * w_s[j] + f1 * w_s[32 + j] + f2 * w_s[64 + j]
                     + f3 * w_s[96 + j] + f4 * w_s[128 + j];
    v[jj] = fmaxf(s, 0.f) * di;
  }
  int u0 = 0, u1 = 0;
  u0 = __builtin_amdgcn_cvt_pk_fp8_f32(v[0], v[1], u0, false);
  u0 = __builtin_amdgcn_cvt_pk_fp8_f32(v[2], v[3], u0, true);
  u1 = __builtin_amdgcn_cvt_pk_fp8_f32(v[4], v[5], u1, false);
  u1 = __builtin_amdgcn_cvt_pk_fp8_f32(v[6], v[7], u1, true);
  *(uint2*)(a.F0 + (size_t)r * 32 + j0) = make_uint2((unsigned)u0, (unsigned)u1);
}

// ---- fused CSR gather + MFMA GEMM, with edge-group (EG) parallel gather.
//      lanes/row = TPR*EG = 8 for all layers: TPR column-slice lanes x EG edge-group
//      lanes walking the uint4 index stream round-robin; partial sums reduced via
//      __shfl_xor within the 8-lane row group. Total gather threads = NN*8 for every
//      K -> machine-filling chains-in-flight even for small K.
//      MODE 0: fp8 out (pre-scaled by dinv); MODE 1: fused mean-pool ----
template<int K, int M, int BROWS, int MODE, int THREADS, int EG>
__global__ __launch_bounds__(THREADS) void kw_fgemm(MegaArgs a,
    const unsigned char* __restrict__ in,
    const _Float16* __restrict__ Wt, const float* __restrict__ bias,
    unsigned char* __restrict__ outp) {
  constexpr int KC = 32;              // one 16x16x32 MFMA consumes 32 k's per chunk
  constexpr int KP = K + 8;
  constexpr int NW = THREADS / 64;    // waves per block
  constexpr int MW = M / NW;          // output cols per wave
  constexpr int CTW = MW / 16;
  constexpr int RT = BROWS / 16;      // row tiles
  constexpr int TPR = K / 16;         // column-slice lanes per row
  constexpr int LPR = TPR * EG;       // total lanes per row
  constexpr int RPP = THREADS / LPR;  // rows per pass
  constexpr int NPASS = (BROWS + RPP - 1) / RPP;
  __shared__ _Float16 a_s[BROWS * KP];
  const int tid = threadIdx.x;
  const int wave = tid >> 6, lane = tid & 63;
  const int m16 = lane & 15, q = lane >> 4;
  const int r0 = blockIdx.x * BROWS;

  // ---- fused gather ----
  {
    const int rowg = tid / LPR;
    const int sub = tid % LPR;
    const int eg = sub / TPR;         // edge group
    const int c = (sub % TPR) * 16;   // fp8-byte column offset within row
    const unsigned char* bp = in + c;
#pragma unroll
    for (int pass = 0; pass < NPASS; ++pass) {
      const int row = pass * RPP + rowg;
      if (NPASS > 1 && row >= BROWS) break;
      const int r = r0 + row;
      f32x2 acc8[8];
#pragma unroll
      for (int i = 0; i < 8; ++i) acc8[i] = (f32x2){0.f, 0.f};
      float di = 0.f;
      if (r < NN) {
        di = a.dinv[r];
        const int eb = a.rowbeg[r];
        const int nIt = (a.rowend[r] - eb + 3) >> 2;
        if (eg == 0) acc16(*(const uint4*)(bp + (size_t)r * K), acc8);  // self term
        const int nL = (EG == 1) ? nIt : (nIt - eg + EG - 1) / EG;
        if (nL > 0) {
          const u32x4* cp = (const u32x4*)(a.csrc + eb) + eg;
          u32x4 i0 = ldnt(cp), i1 = ldnt(cp + EG);
          int k = 0;
          for (; k + 2 <= nL; k += 2) {
            const uint4 f0 = *(const uint4*)(bp + (size_t)i0.x * K);
            const uint4 f1 = *(const uint4*)(bp + (size_t)i0.y * K);
            const uint4 f2 = *(const uint4*)(bp + (size_t)i0.z * K);
            const uint4 f3 = *(const uint4*)(bp + (size_t)i0.w * K);
            const uint4 f4 = *(const uint4*)(bp + (size_t)i1.x * K);
            const uint4 f5 = *(const uint4*)(bp + (size_t)i1.y * K);
            const uint4 f6 = *(const uint4*)(bp + (size_t)i1.z * K);
            const uint4 f7 = *(const uint4*)(bp + (size_t)i1.w * K);
            const u32x4 n0 = ldnt(cp + (k + 2) * EG), n1 = ldnt(cp + (k + 3) * EG);
            acc16(f0, acc8); acc16(f1, acc8); acc16(f2, acc8); acc16(f3, acc8);
            acc16(f4, acc8); acc16(f5, acc8); acc16(f6, acc8); acc16(f7, acc8);
            i0 = n0; i1 = n1;
          }
          if (k < nL) {
            const uint4 f0 = *(const uint4*)(bp + (size_t)i0.x * K);
            const uint4 f1 = *(const uint4*)(bp + (size_t)i0.y * K);
            const uint4 f2 = *(const uint4*)(bp + (size_t)i0.z * K);
            const uint4 f3 = *(const uint4*)(bp + (size_t)i0.w * K);
            acc16(f0, acc8); acc16(f1, acc8); acc16(f2, acc8); acc16(f3, acc8);
          }
        }
      }
      // reduce partial sums across edge-group lanes (stride TPR within 8-lane group)
      if (EG > 1) {
#pragma unroll
        for (int msk = TPR; msk < LPR; msk <<= 1) {
#pragma unroll
          for (int i = 0; i < 8; ++i) {
            acc8[i].x += __shfl_xor(acc8[i].x, msk);
            acc8[i].y += __shfl_xor(acc8[i].y, msk);
          }
        }
      }
      if (EG == 1 || (sub / TPR) == 0) {
        _Float16 h[16];
#pragma unroll
        for (int i = 0; i < 8; ++i) {
          h[2 * i]     = (_Float16)(acc8[i].x * di);
          h[2 * i + 1] = (_Float16)(acc8[i].y * di);
        }
        *(uint4*)&a_s[row * KP + c]     = *(uint4*)&h[0];
        *(uint4*)&a_s[row * KP + c + 8] = *(uint4*)&h[8];
      }
    }
  }
  __syncthreads();

  // ---- GEMM: A from LDS, B direct from global (L2-broadcast), no syncs ----
  f32x4 acc[RT][CTW];
#pragma unroll
  for (int rt = 0; rt < RT; ++rt)
#pragma unroll
    for (int ct = 0; ct < CTW; ++ct) acc[rt][ct] = (f32x4){0.f, 0.f, 0.f, 0.f};

  const _Float16* wp = Wt + (size_t)(wave * MW) * K + q * 8;
#pragma unroll
  for (int kc = 0; kc < K; kc += KC) {
    f16x8 bfr[CTW];
#pragma unroll
    for (int ct = 0; ct < CTW; ++ct)
      bfr[ct] = *(const f16x8*)(wp + (size_t)(ct * 16 + m16) * K + kc);
#pragma unroll
    for (int rt = 0; rt < RT; ++rt) {
      f16x8 afr = *(const f16x8*)&a_s[(rt * 16 + m16) * KP + kc + q * 8];
#pragma unroll
      for (int ct = 0; ct < CTW; ++ct)
        acc[rt][ct] = __builtin_amdgcn_mfma_f32_16x16x32_f16(afr, bfr[ct], acc[rt][ct], 0, 0, 0);
    }
  }

  if constexpr (MODE == 1) {
    const int rlast = (r0 + BROWS - 1 < NN) ? r0 + BROWS - 1 : NN - 1;
    const int bmin = a.batch[r0];
    const int bmax = a.batch[rlast];
    int rowb[RT][4];
#pragma unroll
    for (int rt = 0; rt < RT; ++rt)
#pragma unroll
      for (int reg = 0; reg < 4; ++reg) {
        const int row = r0 + rt * 16 + q * 4 + reg;
        rowb[rt][reg] = (row < NN) ? a.batch[row] : -1;
      }
#pragma unroll
    for (int ct = 0; ct < CTW; ++ct) {
      const int col = wave * MW + ct * 16 + m16;
      const float bv = bias[col];
      for (int b = bmin; b <= bmax; ++b) {
        float s = 0.f;
#pragma unroll
        for (int rt = 0; rt < RT; ++rt)
#pragma unroll
          for (int reg = 0; reg < 4; ++reg)
            if (rowb[rt][reg] == b) s += fmaxf(acc[rt][ct][reg] + bv, 0.f);
        s += __shfl_xor(s, 16);
        s += __shfl_xor(s, 32);
        if (q == 0) atomAdd(&a.pooled[b * M + col], s);
      }
    }
  } else {
#pragma unroll
    for (int rt = 0; rt < RT; ++rt) {
#pragma unroll
      for (int ct = 0; ct < CTW; ++ct) {
        const int col = wave * MW + ct * 16 + m16;
        const float bv = bias[col];
#pragma unroll
        for (int reg = 0; reg < 4; ++reg) {
          const int row = r0 + rt * 16 + q * 4 + reg;
          if (row < NN) {
            float vv = fmaxf(acc[rt][ct][reg] + bv, 0.f) * a.dinv[row];
            outp[(size_t)row * M + col] = f2fp8(vv);
          }
        }
      }
    }
  }
}

// ---- MLP head + log_softmax ----
__global__ __launch_bounds__(256) void kw_mlp(MegaArgs a) {
  __shared__ float p[256];
  __shared__ float h1[100];
  __shared__ float lo[10];
  const int tid = threadIdx.x;
  const int b = blockIdx.x;
  const float inv = 1.0f / fmaxf(a.pcnt[b], 1.0f);
  p[tid] = a.pooled[b * 256 + tid] * inv;
  __syncthreads();
  for (int j = tid; j < 100; j += 256) {
    float s = a.fc1b[j];
    for (int k = 0; k < 256; ++k) s += p[k] * a.fc1w[k * 100 + j];
    h1[j] = fmaxf(s, 0.f);
  }
  __syncthreads();
  if (tid < 10) {
    float s = a.fc2b[tid];
    for (int k = 0; k < 100; ++k) s += h1[k] * a.fc2w[k * 10 + tid];
    lo[tid] = s;
  }
  __syncthreads();
  if (tid == 0) {
    float m = lo[0];
    for (int j = 1; j < 10; ++j) m = fmaxf(m, lo[j]);
    float ssum = 0.f;
    for (int j = 0; j < 10; ++j) ssum += expf(lo[j] - m);
    float lse = m + logf(ssum);
    for (int j = 0; j < 10; ++j) a.out[b * 10 + j] = lo[j] - lse;
  }
}

extern "C" void kernel_launch(void* const* d_in, const int* in_sizes, int n_in,
                              void* d_out, int out_size, void* d_ws, size_t ws_size,
                              hipStream_t stream) {
  const float* x     = (const float*)d_in[0];
  const int*   ei    = (const int*)d_in[1];
  const int*   batch = (const int*)d_in[2];
  const float* W1 = (const float*)d_in[3];  const float* b1 = (const float*)d_in[4];
  const float* W2 = (const float*)d_in[5];  const float* b2 = (const float*)d_in[6];
  const float* W3 = (const float*)d_in[7];  const float* b3 = (const float*)d_in[8];
  const float* W4 = (const float*)d_in[9];  const float* b4 = (const float*)d_in[10];
  const float* fc1w = (const float*)d_in[11]; const float* fc1b = (const float*)d_in[12];
  const float* fc2w = (const float*)d_in[13]; const float* fc2b = (const float*)d_in[14];
  float* out = (float*)d_out;

  const int* src = ei;
  const int* dst = ei + NE;

  // ---- workspace layout (pooled|pcnt|bucketCnt adjacent -> single memset) ----
  float* ws = (float*)d_ws;
  float* pooled = ws;                          // 16384
  float* pcnt   = pooled + 16384;              // 64
  int*   bucketCnt = (int*)(pcnt + 64);        // 512
  float* dinv   = (float*)(bucketCnt + 512);   // 100352
  int*   rowbeg = (int*)(dinv + 100352);       // 100352
  int*   rowend = rowbeg + 100352;             // 100352
  int*   csrc   = rowend + 100352;             // NPAD
  unsigned* pairs = (unsigned*)(csrc + NPAD);  // NPAD (packed u32)
  _Float16* xs8 = (_Float16*)(pairs + NPAD);   // (NN+1)*8 halfs (pad 800768)
  unsigned char* F0 = (unsigned char*)(xs8 + 800768);  // (NN+1)*32 bytes (fp8)
  unsigned char* F1 = F0 + 3200128;                    // (NN+1)*64 bytes (fp8)
  unsigned char* F2 = F1 + 6400128;                    // (NN+1)*128 bytes (fp8)
  _Float16* Wt2 = (_Float16*)(F2 + 12800128);  // 32*64
  _Float16* Wt3 = Wt2 + 32 * 64;               // 64*128
  _Float16* Wt4 = Wt3 + 64 * 128;              // 128*256

  // ---- CSR build (memset + 2 kernels) ----
  (void)hipMemsetAsync(pooled, 0, (16384 + 64 + 512) * sizeof(float), stream);
  k_bin<<<(NE + 4095) / 4096, 256, 0, stream>>>(src, dst, bucketCnt, pairs,
                                                W2, W3, W4, Wt2, Wt3, Wt4);
  k_cntfill<<<NB, 256, 0, stream>>>(pairs, bucketCnt, batch, x,
                                    rowbeg, rowend, dinv, csrc, pcnt, xs8,
                                    F0, F1, F2);

  // ---- compute phases: 8 lanes/row everywhere (col-slice x edge-group) ----
  //  l1   : 4 lanes/row edge-split, 400k threads
  //  K=32 : TPR=2 x EG=4, BROWS=32, 256 thr -> 800k threads
  //  K=64 : TPR=4 x EG=2, BROWS=32, 256 thr -> 800k threads
  //  K=128: TPR=8 x EG=1, BROWS=64, 512 thr -> 800k threads (r7 proven config)
  MegaArgs m;
  m.xs8 = xs8; m.rowbeg = rowbeg; m.rowend = rowend; m.csrc = csrc;
  m.dinv = dinv;
  m.W1 = W1; m.b1 = b1; m.F0 = F0;
  m.Wt2 = Wt2; m.b2 = b2; m.F1 = F1;
  m.Wt3 = Wt3; m.b3 = b3; m.F2 = F2;
  m.Wt4 = Wt4; m.b4 = b4;
  m.batch = batch; m.pooled = pooled; m.pcnt = pcnt;
  m.fc1w = fc1w; m.fc1b = fc1b; m.fc2w = fc2w; m.fc2b = fc2b;
  m.out = out;

  kw_l1<<<(NN * 4 + 255) / 256, 256, 0, stream>>>(m);
  kw_fgemm<32, 64, 32, 0, 256, 4><<<(NN + 31) / 32, 256, 0, stream>>>(m, F0, Wt2, b2, F1);
  kw_fgemm<64, 128, 32, 0, 256, 2><<<(NN + 31) / 32, 256, 0, stream>>>(m, F1, Wt3, b3, F2);
  kw_fgemm<128, 256, 64, 1, 512, 1><<<(NN + 63) / 64, 512, 0, stream>>>(m, F2, Wt4, b4, nullptr);
  kw_mlp<<<NBATCH, 256, 0, stream>>>(m);
}